// Round 8
// baseline (109.505 us; speedup 1.0000x reference)
//
#include <hip/hip_runtime.h>
#include <hip/hip_bf16.h>

typedef __attribute__((ext_vector_type(8))) __bf16 bf16x8;
typedef __attribute__((ext_vector_type(4))) __bf16 bf16x4;
typedef __attribute__((ext_vector_type(4))) float f32x4;

#define DIN 1024
#define DOUT 1024
#define BB 4
#define SS 4096
#define MROWS (BB*SS)   /* 16384 */
#define POOLN 5
#define RR 8
#define NTASKS 5
#define TOPKK 3

// ---------------- K1a: streaming colsum-partials + f32->bf16 convert ----------
// 2048 blocks x 256 threads. Unit = 8 floats (32B read, 16B bf16 store).
// Thread handles units tid + i*524288, i<4 (stride ==0 mod 128 units -> thread's
// 8 columns constant). Per-block partials: [block][subrow 0..1][1024] f32,
// written as 2 coalesced float4 per thread. No atomics anywhere.
__global__ __launch_bounds__(256) void k1a_stream(const float* __restrict__ in,
                                                  __bf16* __restrict__ inB,
                                                  float* __restrict__ partial) {
    const int t = threadIdx.x;
    const int b = blockIdx.x;
    const int tid = b * 256 + t;                         // 0..524287
    const float4* __restrict__ inv = (const float4*)in;
    bf16x8* __restrict__ outv = (bf16x8*)inB;

    float s0=0.f,s1=0.f,s2=0.f,s3=0.f,s4=0.f,s5=0.f,s6=0.f,s7=0.f;
    float4 va = inv[2*(size_t)tid];
    float4 vb = inv[2*(size_t)tid + 1];
#pragma unroll
    for (int i = 0; i < 4; ++i) {
        float4 na = va, nb = vb;
        if (i < 3) {
            const size_t u = (size_t)tid + (size_t)(i+1) * 524288;
            na = inv[2*u]; nb = inv[2*u + 1];
        }
        s0 += va.x; s1 += va.y; s2 += va.z; s3 += va.w;
        s4 += vb.x; s5 += vb.y; s6 += vb.z; s7 += vb.w;
        bf16x8 o = { (__bf16)va.x, (__bf16)va.y, (__bf16)va.z, (__bf16)va.w,
                     (__bf16)vb.x, (__bf16)vb.y, (__bf16)vb.z, (__bf16)vb.w };
        outv[(size_t)tid + (size_t)i * 524288] = o;
        va = na; vb = nb;
    }
    const int c0 = (t & 127) * 8;                        // thread's 8 columns
    const int sr = t >> 7;                               // sub-row 0/1
    float* dst = &partial[((size_t)b * 2 + sr) * DIN + c0];
    float4 p0 = { s0, s1, s2, s3 };
    float4 p1 = { s4, s5, s6, s7 };
    *(float4*)dst = p0;
    *(float4*)(dst + 4) = p1;
}

// ---------------- K1b: reduce partial[4096][1024] -> partial2[8][1024] --------
// 32 blocks x 256 threads; thread (g,c) sums 512 rows of column c. Coalesced,
// no atomics, no memset dependency.
__global__ __launch_bounds__(256) void k1b_reduce(const float* __restrict__ partial,
                                                  float* __restrict__ partial2) {
    const int tid = blockIdx.x * 256 + threadIdx.x;      // 0..8191
    const int c = tid & (DIN - 1);
    const int g = tid >> 10;                             // 0..7
    float s = 0.f;
    const int r0 = g * 512;
#pragma unroll 8
    for (int r = r0; r < r0 + 512; ++r)
        s += partial[(size_t)r * DIN + c];
    partial2[(size_t)g * DIN + c] = s;
}

// ---------------- K2: omegas -> top-k -> softmax gate (4 waves) ----------------
__global__ void k2_gate(const float* __restrict__ partial2,
                        const float* __restrict__ lroute,
                        const int* __restrict__ task_id_p,
                        float* __restrict__ gate, int* __restrict__ gidx) {
    __shared__ float red[4][POOLN];
    const int tix = threadIdx.x;        // 0..255
    const int w = tix >> 6, l = tix & 63;
    float part[POOLN] = {0.f, 0.f, 0.f, 0.f, 0.f};
    for (int d = w * 256 + l; d < w * 256 + 256; d += 64) {
        float cs = 0.f;
#pragma unroll
        for (int g = 0; g < 8; ++g) cs += partial2[g * DIN + d];
        cs *= (1.0f / (float)MROWS);
        const float* rp = &lroute[(size_t)1 * DIN * POOLN + (size_t)d * POOLN];
#pragma unroll
        for (int p = 0; p < POOLN; ++p) part[p] += cs * rp[p];
    }
#pragma unroll
    for (int p = 0; p < POOLN; ++p) {
        float v = part[p];
        for (int off = 32; off; off >>= 1) v += __shfl_down(v, off);
        if (l == 0) red[w][p] = v;
    }
    __syncthreads();
    if (tix == 0) {
#pragma unroll
        for (int p = 0; p < POOLN; ++p)
            part[p] = red[0][p] + red[1][p] + red[2][p] + red[3][p];
        int tid = *task_id_p;
        if (tid > NTASKS) tid = NTASKS;
        int L = tid < (POOLN - 1) ? tid : (POOLN - 1);   // slice [1:tid+1] clamps
        int k = tid < TOPKK ? tid : TOPKK;
        float sl[POOLN];
        for (int j = 0; j < L; ++j) sl[j] = part[1 + j];
        float G[TOPKK]; int I[TOPKK];
        int used = 0;
        for (int j = 0; j < k; ++j) {
            int best = -1; float bv = 0.f;
            for (int i2 = 0; i2 < L; ++i2) {
                if (used & (1 << i2)) continue;
                if (best < 0 || sl[i2] > bv) { bv = sl[i2]; best = i2; }
            }
            used |= 1 << best; G[j] = bv; I[j] = best;
        }
        if (k > 0) {
            float m = G[0];           // descending -> max first
            float e[TOPKK]; float se = 0.f;
            for (int j = 0; j < k; ++j) { e[j] = expf(G[j] - m); se += e[j]; }
            for (int j = 0; j < k; ++j) { gate[j] = e[j] / se; gidx[j] = I[j]; }
        }
        for (int j = k; j < TOPKK; ++j) { gate[j] = 0.f; gidx[j] = 0; }
    }
}

// ---------------- K3: build two bf16 B^T weight matrices ----------------
__global__ __launch_bounds__(256) void k3_weights(const float* __restrict__ W,
                                                  const float* __restrict__ ldown,
                                                  const float* __restrict__ lup,
                                                  const float* __restrict__ gate,
                                                  const int* __restrict__ gidx,
                                                  __bf16* __restrict__ Wb0,
                                                  __bf16* __restrict__ Wb1) {
    const int o = blockIdx.x;
    const int t = threadIdx.x;
    float c[TOPKK][RR];
#pragma unroll
    for (int j = 0; j < TOPKK; ++j) {
        const float g = gate[j];
        const int   p = gidx[j];
#pragma unroll
        for (int r = 0; r < RR; ++r)
            c[j][r] = g * lup[(size_t)p * RR * DOUT + (size_t)r * DOUT + o];
    }
    const int d0 = t * 4;
    const float4 wv = *(const float4*)&W[(size_t)o * DIN + d0];
    float outv[4] = { wv.x, wv.y, wv.z, wv.w };
    float dwv[4]  = { 0.f, 0.f, 0.f, 0.f };
#pragma unroll
    for (int j = 0; j < TOPKK; ++j) {
        const int p = gidx[j];
#pragma unroll
        for (int dd = 0; dd < 4; ++dd) {
            const float4 da = *(const float4*)&ldown[(size_t)p * DIN * RR + (size_t)(d0 + dd) * RR];
            const float4 db = *(const float4*)&ldown[(size_t)p * DIN * RR + (size_t)(d0 + dd) * RR + 4];
            dwv[dd] += da.x * c[j][0] + da.y * c[j][1] + da.z * c[j][2] + da.w * c[j][3]
                     + db.x * c[j][4] + db.y * c[j][5] + db.z * c[j][6] + db.w * c[j][7];
        }
    }
    bf16x4 b0 = { (__bf16)outv[0], (__bf16)outv[1], (__bf16)outv[2], (__bf16)outv[3] };
    bf16x4 b1 = { (__bf16)(outv[0] + dwv[0]), (__bf16)(outv[1] + dwv[1]),
                  (__bf16)(outv[2] + dwv[2]), (__bf16)(outv[3] + dwv[3]) };
    *(bf16x4*)&Wb0[(size_t)o * DIN + d0] = b0;
    *(bf16x4*)&Wb1[(size_t)o * DIN + d0] = b1;
}

// ---------------- K4: 128x256 bf16 MFMA GEMM, depth-3 slabs, 2 blocks/CU ------
// (unchanged from R7 — 43.5us, 790 TF, 0 bank conflicts)
__global__ __launch_bounds__(512, 4) void k4_gemm(const __bf16* __restrict__ A,
                                                  const __bf16* __restrict__ B0,
                                                  const __bf16* __restrict__ B1,
                                                  float* __restrict__ C) {
    __shared__ ushort lds[36864];              // 72 KB; slab p at p*12288 ushorts
    const int bid = blockIdx.x;                // 0..511
    const int xcd = bid & 7;
    const int idx = bid >> 3;                  // 0..63
    const int tm  = xcd * 16 + (idx >> 2);     // 0..127 ; same-XCD blocks share A-panels
    const int tn  = idx & 3;                   // 0..3
    const __bf16* __restrict__ Bt = (tm >= 64) ? B1 : B0;   // rows >= 8192 get +delta

    const int lane = threadIdx.x & 63;
    const int wid  = threadIdx.x >> 6;         // 0..7
    const int wm = wid >> 2, wn = wid & 3;     // 2M x 4N wave grid

    const int rpl  = lane >> 3;                // local rowpair 0..7
    const int sl   = (lane & 7) ^ rpl;         // logical c + 4*parity
    const int srow = rpl * 2 + (sl >> 2);      // 0..15
    const int sc   = sl & 3;                   // 16B k-chunk

    const char* gA = (const char*)A  + ((size_t)(tm*128 + wid*16 + srow)) * 2048 + sc * 16;
    const char* gB = (const char*)Bt + ((size_t)(tn*256 + wid*32 + srow)) * 2048 + sc * 16;
    const int ldsAst = wid * 512;              // ushort idx within A region
    const int ldsBst = 4096 + wid * 1024;      // ushort idx within slab (B region)

    const int rhalf = (lane & 15) >> 1;
    const int slot  = ((lane >> 4) + 4 * (lane & 1)) ^ rhalf;
    const int aoff  = (wm * 32 + rhalf) * 64 + slot * 8;          // + p*12288 + mi*512
    const int boff  = 4096 + (wn * 32 + rhalf) * 64 + slot * 8;   // + p*12288 + ni*512

    f32x4 acc[4][4];
#pragma unroll
    for (int i = 0; i < 4; ++i)
#pragma unroll
        for (int j = 0; j < 4; ++j) acc[i][j] = (f32x4){0.f, 0.f, 0.f, 0.f};

    auto stageSlab = [&](int s) {
        const int p = s % 3;
        const size_t kb = (size_t)s * 64;      // 32 bf16 = 64 B per k-slab
        __builtin_amdgcn_global_load_lds(
            (const __attribute__((address_space(1))) void*)(gA + kb),
            (__attribute__((address_space(3))) void*)&lds[p * 12288 + ldsAst],
            16, 0, 0);
#pragma unroll
        for (int j = 0; j < 2; ++j) {
            __builtin_amdgcn_global_load_lds(
                (const __attribute__((address_space(1))) void*)(gB + (size_t)j * 32768 + kb),
                (__attribute__((address_space(3))) void*)&lds[p * 12288 + ldsBst + j * 512],
                16, 0, 0);
        }
    };

    auto computeSlab = [&](int s) {
        const int p = s % 3;
        const ushort* aB = &lds[p * 12288 + aoff];
        const ushort* bB = &lds[p * 12288 + boff];
        bf16x8 a[4], b[4];
#pragma unroll
        for (int mi = 0; mi < 4; ++mi) a[mi] = *(const bf16x8*)(aB + mi * 512);
#pragma unroll
        for (int ni = 0; ni < 4; ++ni) b[ni] = *(const bf16x8*)(bB + ni * 512);
        __builtin_amdgcn_s_setprio(1);
#pragma unroll
        for (int mi = 0; mi < 4; ++mi)
#pragma unroll
            for (int ni = 0; ni < 4; ++ni)
                acc[mi][ni] = __builtin_amdgcn_mfma_f32_16x16x32_bf16(
                    a[mi], b[ni], acc[mi][ni], 0, 0, 0);
        __builtin_amdgcn_s_setprio(0);
    };

    stageSlab(0); stageSlab(1);

#define K4_STEP(S, NSTR, DOSTAGE)                                     \
    {                                                                 \
        if (DOSTAGE) stageSlab((S) + 2);                              \
        asm volatile("s_waitcnt vmcnt(" NSTR ")" ::: "memory");       \
        __builtin_amdgcn_s_barrier();                                 \
        asm volatile("" ::: "memory");                                \
        computeSlab(S);                                               \
        asm volatile("" ::: "memory");                                \
        __builtin_amdgcn_s_barrier();                                 \
    }

#pragma unroll 1
    for (int s = 0; s < 30; ++s) K4_STEP(s, "6", true);
    K4_STEP(30, "3", false);
    K4_STEP(31, "0", false);
#undef K4_STEP

#pragma unroll
    for (int mi = 0; mi < 4; ++mi) {
#pragma unroll
        for (int r = 0; r < 4; ++r) {
            const int grow = tm * 128 + wm * 64 + mi * 16 + (lane >> 4) * 4 + r;
            float* cp = C + (size_t)grow * 1024 + tn * 256 + wn * 64 + (lane & 15);
#pragma unroll
            for (int ni = 0; ni < 4; ++ni) cp[ni * 16] = acc[mi][ni][r];
        }
    }
}

extern "C" void kernel_launch(void* const* d_in, const int* in_sizes, int n_in,
                              void* d_out, int out_size, void* d_ws, size_t ws_size,
                              hipStream_t stream) {
    const float* in     = (const float*)d_in[0];
    const float* W      = (const float*)d_in[1];
    const float* ldown  = (const float*)d_in[2];
    const float* lup    = (const float*)d_in[3];
    const float* lroute = (const float*)d_in[4];
    const int*   taskid = (const int*)d_in[5];
    float* out = (float*)d_out;

    // workspace carve (~36.7 MB)
    __bf16* inB     = (__bf16*)d_ws;                            // 32 MB
    __bf16* Wb0     = inB + (size_t)MROWS * DIN;                // 2 MB
    __bf16* Wb1     = Wb0 + (size_t)DOUT * DIN;                 // 2 MB
    float*  partial2= (float*)(Wb1 + (size_t)DOUT * DIN);       // 32 KB
    float*  gate    = partial2 + 8 * DIN;
    int*    gidx    = (int*)(gate + TOPKK);

    // per-block partials [4096][1024] f32 = 16 MB live in d_out (64 MB);
    // k4 fully overwrites d_out afterwards -> deterministic, zero ws cost.
    float* partial = out;

    k1a_stream<<<2048, 256, 0, stream>>>(in, inB, partial);
    k1b_reduce<<<32, 256, 0, stream>>>(partial, partial2);
    k2_gate<<<1, 256, 0, stream>>>(partial2, lroute, taskid, gate, gidx);
    k3_weights<<<1024, 256, 0, stream>>>(W, ldown, lup, gate, gidx, Wb0, Wb1);
    k4_gemm<<<512, 512, 0, stream>>>(inB, Wb0, Wb1, out);
}

// Round 10
// 100.840 us; speedup vs baseline: 1.0859x; 1.0859x over previous
//
#include <hip/hip_runtime.h>
#include <hip/hip_bf16.h>

typedef __attribute__((ext_vector_type(8))) __bf16 bf16x8;
typedef __attribute__((ext_vector_type(4))) __bf16 bf16x4;
typedef __attribute__((ext_vector_type(4))) float f32x4;

#define DIN 1024
#define DOUT 1024
#define BB 4
#define SS 4096
#define MROWS (BB*SS)   /* 16384 */
#define POOLN 5
#define RR 8
#define NTASKS 5
#define TOPKK 3

// ---------------- K1a: streaming colsum-partials + f32->bf16 convert ----------
// 2048 blocks x 256 threads. TWO independent streams per thread (A: first 32MB,
// B: second 32MB), each contiguous-coalesced float4, prefetch-by-one -> up to
// 4 loads + 2 stores in flight per thread. Stream stride 524288 float4 == 0
// mod 256 -> thread's 4 columns constant across both streams (B base 2M float4
// == 0 mod 256 too). Per-block partials: 1 float4/thread, coalesced. No atomics.
// Nontemporal loads: input is read-once; don't evict inB/Wb from L3.
__global__ __launch_bounds__(256) void k1a_stream(const float* __restrict__ in,
                                                  __bf16* __restrict__ inB,
                                                  float* __restrict__ partial) {
    const int t = threadIdx.x;
    const int b = blockIdx.x;
    const int tid = b * 256 + t;                         // 0..524287
    const f32x4* __restrict__ inv = (const f32x4*)in;    // ext_vector for nontemporal
    bf16x4* __restrict__ outv = (bf16x4*)inB;

    float s0 = 0.f, s1 = 0.f, s2 = 0.f, s3 = 0.f;
    size_t ia = (size_t)tid;                             // stream A
    size_t ib = (size_t)tid + 2097152;                   // stream B (half-buffer)
    f32x4 ca = __builtin_nontemporal_load(&inv[ia]);
    f32x4 cb = __builtin_nontemporal_load(&inv[ib]);
#pragma unroll
    for (int i = 0; i < 4; ++i) {
        f32x4 na = ca, nb = cb;
        if (i < 3) {
            na = __builtin_nontemporal_load(&inv[ia + 524288]);
            nb = __builtin_nontemporal_load(&inv[ib + 524288]);
        }
        s0 += ca[0] + cb[0]; s1 += ca[1] + cb[1];
        s2 += ca[2] + cb[2]; s3 += ca[3] + cb[3];
        bf16x4 oa = { (__bf16)ca[0], (__bf16)ca[1], (__bf16)ca[2], (__bf16)ca[3] };
        bf16x4 ob = { (__bf16)cb[0], (__bf16)cb[1], (__bf16)cb[2], (__bf16)cb[3] };
        outv[ia] = oa;
        outv[ib] = ob;
        ca = na; cb = nb;
        ia += 524288; ib += 524288;
    }
    const int c0 = (t * 4) & (DIN - 1);                  // block covers all 1024 cols
    f32x4 p = { s0, s1, s2, s3 };
    *(f32x4*)&partial[(size_t)b * DIN + c0] = p;         // coalesced float4 store
}

// ---------------- K1b: reduce partial[2048][1024] -> partial2[8][1024] --------
// 32 blocks x 256 threads; thread (g,c) sums 256 rows of column c. Coalesced,
// no atomics, no memset dependency.
__global__ __launch_bounds__(256) void k1b_reduce(const float* __restrict__ partial,
                                                  float* __restrict__ partial2) {
    const int tid = blockIdx.x * 256 + threadIdx.x;      // 0..8191
    const int c = tid & (DIN - 1);
    const int g = tid >> 10;                             // 0..7
    float s = 0.f;
    const int r0 = g * 256;
#pragma unroll 8
    for (int r = r0; r < r0 + 256; ++r)
        s += partial[(size_t)r * DIN + c];
    partial2[(size_t)g * DIN + c] = s;
}

// ---------------- K2: omegas -> top-k -> softmax gate (4 waves) ----------------
__global__ void k2_gate(const float* __restrict__ partial2,
                        const float* __restrict__ lroute,
                        const int* __restrict__ task_id_p,
                        float* __restrict__ gate, int* __restrict__ gidx) {
    __shared__ float red[4][POOLN];
    const int tix = threadIdx.x;        // 0..255
    const int w = tix >> 6, l = tix & 63;
    float part[POOLN] = {0.f, 0.f, 0.f, 0.f, 0.f};
    for (int d = w * 256 + l; d < w * 256 + 256; d += 64) {
        float cs = 0.f;
#pragma unroll
        for (int g = 0; g < 8; ++g) cs += partial2[g * DIN + d];
        cs *= (1.0f / (float)MROWS);
        const float* rp = &lroute[(size_t)1 * DIN * POOLN + (size_t)d * POOLN];
#pragma unroll
        for (int p = 0; p < POOLN; ++p) part[p] += cs * rp[p];
    }
#pragma unroll
    for (int p = 0; p < POOLN; ++p) {
        float v = part[p];
        for (int off = 32; off; off >>= 1) v += __shfl_down(v, off);
        if (l == 0) red[w][p] = v;
    }
    __syncthreads();
    if (tix == 0) {
#pragma unroll
        for (int p = 0; p < POOLN; ++p)
            part[p] = red[0][p] + red[1][p] + red[2][p] + red[3][p];
        int tid = *task_id_p;
        if (tid > NTASKS) tid = NTASKS;
        int L = tid < (POOLN - 1) ? tid : (POOLN - 1);   // slice [1:tid+1] clamps
        int k = tid < TOPKK ? tid : TOPKK;
        float sl[POOLN];
        for (int j = 0; j < L; ++j) sl[j] = part[1 + j];
        float G[TOPKK]; int I[TOPKK];
        int used = 0;
        for (int j = 0; j < k; ++j) {
            int best = -1; float bv = 0.f;
            for (int i2 = 0; i2 < L; ++i2) {
                if (used & (1 << i2)) continue;
                if (best < 0 || sl[i2] > bv) { bv = sl[i2]; best = i2; }
            }
            used |= 1 << best; G[j] = bv; I[j] = best;
        }
        if (k > 0) {
            float m = G[0];           // descending -> max first
            float e[TOPKK]; float se = 0.f;
            for (int j = 0; j < k; ++j) { e[j] = expf(G[j] - m); se += e[j]; }
            for (int j = 0; j < k; ++j) { gate[j] = e[j] / se; gidx[j] = I[j]; }
        }
        for (int j = k; j < TOPKK; ++j) { gate[j] = 0.f; gidx[j] = 0; }
    }
}

// ---------------- K3: build two bf16 B^T weight matrices ----------------
__global__ __launch_bounds__(256) void k3_weights(const float* __restrict__ W,
                                                  const float* __restrict__ ldown,
                                                  const float* __restrict__ lup,
                                                  const float* __restrict__ gate,
                                                  const int* __restrict__ gidx,
                                                  __bf16* __restrict__ Wb0,
                                                  __bf16* __restrict__ Wb1) {
    const int o = blockIdx.x;
    const int t = threadIdx.x;
    float c[TOPKK][RR];
#pragma unroll
    for (int j = 0; j < TOPKK; ++j) {
        const float g = gate[j];
        const int   p = gidx[j];
#pragma unroll
        for (int r = 0; r < RR; ++r)
            c[j][r] = g * lup[(size_t)p * RR * DOUT + (size_t)r * DOUT + o];
    }
    const int d0 = t * 4;
    const float4 wv = *(const float4*)&W[(size_t)o * DIN + d0];
    float outv[4] = { wv.x, wv.y, wv.z, wv.w };
    float dwv[4]  = { 0.f, 0.f, 0.f, 0.f };
#pragma unroll
    for (int j = 0; j < TOPKK; ++j) {
        const int p = gidx[j];
#pragma unroll
        for (int dd = 0; dd < 4; ++dd) {
            const float4 da = *(const float4*)&ldown[(size_t)p * DIN * RR + (size_t)(d0 + dd) * RR];
            const float4 db = *(const float4*)&ldown[(size_t)p * DIN * RR + (size_t)(d0 + dd) * RR + 4];
            dwv[dd] += da.x * c[j][0] + da.y * c[j][1] + da.z * c[j][2] + da.w * c[j][3]
                     + db.x * c[j][4] + db.y * c[j][5] + db.z * c[j][6] + db.w * c[j][7];
        }
    }
    bf16x4 b0 = { (__bf16)outv[0], (__bf16)outv[1], (__bf16)outv[2], (__bf16)outv[3] };
    bf16x4 b1 = { (__bf16)(outv[0] + dwv[0]), (__bf16)(outv[1] + dwv[1]),
                  (__bf16)(outv[2] + dwv[2]), (__bf16)(outv[3] + dwv[3]) };
    *(bf16x4*)&Wb0[(size_t)o * DIN + d0] = b0;
    *(bf16x4*)&Wb1[(size_t)o * DIN + d0] = b1;
}

// ---------------- K4: 128x256 bf16 MFMA GEMM, depth-3 slabs, 2 blocks/CU ------
// (unchanged from R7 — 43.5us, 790 TF, 0 bank conflicts)
__global__ __launch_bounds__(512, 4) void k4_gemm(const __bf16* __restrict__ A,
                                                  const __bf16* __restrict__ B0,
                                                  const __bf16* __restrict__ B1,
                                                  float* __restrict__ C) {
    __shared__ ushort lds[36864];              // 72 KB; slab p at p*12288 ushorts
    const int bid = blockIdx.x;                // 0..511
    const int xcd = bid & 7;
    const int idx = bid >> 3;                  // 0..63
    const int tm  = xcd * 16 + (idx >> 2);     // 0..127 ; same-XCD blocks share A-panels
    const int tn  = idx & 3;                   // 0..3
    const __bf16* __restrict__ Bt = (tm >= 64) ? B1 : B0;   // rows >= 8192 get +delta

    const int lane = threadIdx.x & 63;
    const int wid  = threadIdx.x >> 6;         // 0..7
    const int wm = wid >> 2, wn = wid & 3;     // 2M x 4N wave grid

    const int rpl  = lane >> 3;                // local rowpair 0..7
    const int sl   = (lane & 7) ^ rpl;         // logical c + 4*parity
    const int srow = rpl * 2 + (sl >> 2);      // 0..15
    const int sc   = sl & 3;                   // 16B k-chunk

    const char* gA = (const char*)A  + ((size_t)(tm*128 + wid*16 + srow)) * 2048 + sc * 16;
    const char* gB = (const char*)Bt + ((size_t)(tn*256 + wid*32 + srow)) * 2048 + sc * 16;
    const int ldsAst = wid * 512;              // ushort idx within A region
    const int ldsBst = 4096 + wid * 1024;      // ushort idx within slab (B region)

    const int rhalf = (lane & 15) >> 1;
    const int slot  = ((lane >> 4) + 4 * (lane & 1)) ^ rhalf;
    const int aoff  = (wm * 32 + rhalf) * 64 + slot * 8;          // + p*12288 + mi*512
    const int boff  = 4096 + (wn * 32 + rhalf) * 64 + slot * 8;   // + p*12288 + ni*512

    f32x4 acc[4][4];
#pragma unroll
    for (int i = 0; i < 4; ++i)
#pragma unroll
        for (int j = 0; j < 4; ++j) acc[i][j] = (f32x4){0.f, 0.f, 0.f, 0.f};

    auto stageSlab = [&](int s) {
        const int p = s % 3;
        const size_t kb = (size_t)s * 64;      // 32 bf16 = 64 B per k-slab
        __builtin_amdgcn_global_load_lds(
            (const __attribute__((address_space(1))) void*)(gA + kb),
            (__attribute__((address_space(3))) void*)&lds[p * 12288 + ldsAst],
            16, 0, 0);
#pragma unroll
        for (int j = 0; j < 2; ++j) {
            __builtin_amdgcn_global_load_lds(
                (const __attribute__((address_space(1))) void*)(gB + (size_t)j * 32768 + kb),
                (__attribute__((address_space(3))) void*)&lds[p * 12288 + ldsBst + j * 512],
                16, 0, 0);
        }
    };

    auto computeSlab = [&](int s) {
        const int p = s % 3;
        const ushort* aB = &lds[p * 12288 + aoff];
        const ushort* bB = &lds[p * 12288 + boff];
        bf16x8 a[4], b[4];
#pragma unroll
        for (int mi = 0; mi < 4; ++mi) a[mi] = *(const bf16x8*)(aB + mi * 512);
#pragma unroll
        for (int ni = 0; ni < 4; ++ni) b[ni] = *(const bf16x8*)(bB + ni * 512);
        __builtin_amdgcn_s_setprio(1);
#pragma unroll
        for (int mi = 0; mi < 4; ++mi)
#pragma unroll
            for (int ni = 0; ni < 4; ++ni)
                acc[mi][ni] = __builtin_amdgcn_mfma_f32_16x16x32_bf16(
                    a[mi], b[ni], acc[mi][ni], 0, 0, 0);
        __builtin_amdgcn_s_setprio(0);
    };

    stageSlab(0); stageSlab(1);

#define K4_STEP(S, NSTR, DOSTAGE)                                     \
    {                                                                 \
        if (DOSTAGE) stageSlab((S) + 2);                              \
        asm volatile("s_waitcnt vmcnt(" NSTR ")" ::: "memory");       \
        __builtin_amdgcn_s_barrier();                                 \
        asm volatile("" ::: "memory");                                \
        computeSlab(S);                                               \
        asm volatile("" ::: "memory");                                \
        __builtin_amdgcn_s_barrier();                                 \
    }

#pragma unroll 1
    for (int s = 0; s < 30; ++s) K4_STEP(s, "6", true);
    K4_STEP(30, "3", false);
    K4_STEP(31, "0", false);
#undef K4_STEP

#pragma unroll
    for (int mi = 0; mi < 4; ++mi) {
#pragma unroll
        for (int r = 0; r < 4; ++r) {
            const int grow = tm * 128 + wm * 64 + mi * 16 + (lane >> 4) * 4 + r;
            float* cp = C + (size_t)grow * 1024 + tn * 256 + wn * 64 + (lane & 15);
#pragma unroll
            for (int ni = 0; ni < 4; ++ni) cp[ni * 16] = acc[mi][ni][r];
        }
    }
}

extern "C" void kernel_launch(void* const* d_in, const int* in_sizes, int n_in,
                              void* d_out, int out_size, void* d_ws, size_t ws_size,
                              hipStream_t stream) {
    const float* in     = (const float*)d_in[0];
    const float* W      = (const float*)d_in[1];
    const float* ldown  = (const float*)d_in[2];
    const float* lup    = (const float*)d_in[3];
    const float* lroute = (const float*)d_in[4];
    const int*   taskid = (const int*)d_in[5];
    float* out = (float*)d_out;

    // workspace carve (~36.7 MB)
    __bf16* inB     = (__bf16*)d_ws;                            // 32 MB
    __bf16* Wb0     = inB + (size_t)MROWS * DIN;                // 2 MB
    __bf16* Wb1     = Wb0 + (size_t)DOUT * DIN;                 // 2 MB
    float*  partial2= (float*)(Wb1 + (size_t)DOUT * DIN);       // 32 KB
    float*  gate    = partial2 + 8 * DIN;
    int*    gidx    = (int*)(gate + TOPKK);

    // per-block partials [2048][1024] f32 = 8 MB live in d_out (64 MB);
    // k4 fully overwrites d_out afterwards -> deterministic, zero ws cost.
    float* partial = out;

    k1a_stream<<<2048, 256, 0, stream>>>(in, inB, partial);
    k1b_reduce<<<32, 256, 0, stream>>>(partial, partial2);
    k2_gate<<<1, 256, 0, stream>>>(partial2, lroute, taskid, gate, gidx);
    k3_weights<<<1024, 256, 0, stream>>>(W, ldown, lup, gate, gidx, Wb0, Wb1);
    k4_gemm<<<512, 512, 0, stream>>>(inB, Wb0, Wb1, out);
}

// Round 11
// 94.413 us; speedup vs baseline: 1.1599x; 1.0681x over previous
//
#include <hip/hip_runtime.h>
#include <hip/hip_bf16.h>

typedef __attribute__((ext_vector_type(8))) __bf16 bf16x8;
typedef __attribute__((ext_vector_type(4))) __bf16 bf16x4;
typedef __attribute__((ext_vector_type(4))) float f32x4;

#define DIN 1024
#define DOUT 1024
#define BB 4
#define SS 4096
#define MROWS (BB*SS)   /* 16384 */
#define POOLN 5
#define RR 8
#define NTASKS 5
#define TOPKK 3

// ---------------- KA: colsum partials ONLY (pure 64MB read) -------------------
// 2048 blocks x 256 threads, grid-stride 8 iters, stride 524288 float4 (==0 mod
// 256) -> thread's 4 columns constant. Input stays L3-warm for k4's A-reads.
__global__ __launch_bounds__(256) void kA_colsum(const float* __restrict__ in,
                                                 float* __restrict__ partial) {
    const int t = threadIdx.x;
    const int b = blockIdx.x;
    const int idx0 = b * 256 + t;                        // 0..524287
    const f32x4* __restrict__ inv = (const f32x4*)in;

    float s0 = 0.f, s1 = 0.f, s2 = 0.f, s3 = 0.f;
    size_t idx = idx0;
    f32x4 cur = inv[idx];
#pragma unroll
    for (int i = 0; i < 8; ++i) {
        f32x4 nxt = cur;
        if (i < 7) nxt = inv[idx + 524288];
        s0 += cur[0]; s1 += cur[1]; s2 += cur[2]; s3 += cur[3];
        cur = nxt;
        idx += 524288;
    }
    const int c0 = (t * 4) & (DIN - 1);
    f32x4 p = { s0, s1, s2, s3 };
    *(f32x4*)&partial[(size_t)b * DIN + c0] = p;
}

// ---------------- K1b: reduce partial[2048][1024] -> partial2[8][1024] --------
__global__ __launch_bounds__(256) void k1b_reduce(const float* __restrict__ partial,
                                                  float* __restrict__ partial2) {
    const int tid = blockIdx.x * 256 + threadIdx.x;      // 0..8191
    const int c = tid & (DIN - 1);
    const int g = tid >> 10;                             // 0..7
    float s = 0.f;
    const int r0 = g * 256;
#pragma unroll 8
    for (int r = r0; r < r0 + 256; ++r)
        s += partial[(size_t)r * DIN + c];
    partial2[(size_t)g * DIN + c] = s;
}

// ---------------- K2: omegas -> top-k -> softmax gate (4 waves) ----------------
__global__ void k2_gate(const float* __restrict__ partial2,
                        const float* __restrict__ lroute,
                        const int* __restrict__ task_id_p,
                        float* __restrict__ gate, int* __restrict__ gidx) {
    __shared__ float red[4][POOLN];
    const int tix = threadIdx.x;        // 0..255
    const int w = tix >> 6, l = tix & 63;
    float part[POOLN] = {0.f, 0.f, 0.f, 0.f, 0.f};
    for (int d = w * 256 + l; d < w * 256 + 256; d += 64) {
        float cs = 0.f;
#pragma unroll
        for (int g = 0; g < 8; ++g) cs += partial2[g * DIN + d];
        cs *= (1.0f / (float)MROWS);
        const float* rp = &lroute[(size_t)1 * DIN * POOLN + (size_t)d * POOLN];
#pragma unroll
        for (int p = 0; p < POOLN; ++p) part[p] += cs * rp[p];
    }
#pragma unroll
    for (int p = 0; p < POOLN; ++p) {
        float v = part[p];
        for (int off = 32; off; off >>= 1) v += __shfl_down(v, off);
        if (l == 0) red[w][p] = v;
    }
    __syncthreads();
    if (tix == 0) {
#pragma unroll
        for (int p = 0; p < POOLN; ++p)
            part[p] = red[0][p] + red[1][p] + red[2][p] + red[3][p];
        int tid = *task_id_p;
        if (tid > NTASKS) tid = NTASKS;
        int L = tid < (POOLN - 1) ? tid : (POOLN - 1);   // slice [1:tid+1] clamps
        int k = tid < TOPKK ? tid : TOPKK;
        float sl[POOLN];
        for (int j = 0; j < L; ++j) sl[j] = part[1 + j];
        float G[TOPKK]; int I[TOPKK];
        int used = 0;
        for (int j = 0; j < k; ++j) {
            int best = -1; float bv = 0.f;
            for (int i2 = 0; i2 < L; ++i2) {
                if (used & (1 << i2)) continue;
                if (best < 0 || sl[i2] > bv) { bv = sl[i2]; best = i2; }
            }
            used |= 1 << best; G[j] = bv; I[j] = best;
        }
        if (k > 0) {
            float m = G[0];           // descending -> max first
            float e[TOPKK]; float se = 0.f;
            for (int j = 0; j < k; ++j) { e[j] = expf(G[j] - m); se += e[j]; }
            for (int j = 0; j < k; ++j) { gate[j] = e[j] / se; gidx[j] = I[j]; }
        }
        for (int j = k; j < TOPKK; ++j) { gate[j] = 0.f; gidx[j] = 0; }
    }
}

// ---------------- K3: build two bf16 B^T weight matrices ----------------
__global__ __launch_bounds__(256) void k3_weights(const float* __restrict__ W,
                                                  const float* __restrict__ ldown,
                                                  const float* __restrict__ lup,
                                                  const float* __restrict__ gate,
                                                  const int* __restrict__ gidx,
                                                  __bf16* __restrict__ Wb0,
                                                  __bf16* __restrict__ Wb1) {
    const int o = blockIdx.x;
    const int t = threadIdx.x;
    float c[TOPKK][RR];
#pragma unroll
    for (int j = 0; j < TOPKK; ++j) {
        const float g = gate[j];
        const int   p = gidx[j];
#pragma unroll
        for (int r = 0; r < RR; ++r)
            c[j][r] = g * lup[(size_t)p * RR * DOUT + (size_t)r * DOUT + o];
    }
    const int d0 = t * 4;
    const float4 wv = *(const float4*)&W[(size_t)o * DIN + d0];
    float outv[4] = { wv.x, wv.y, wv.z, wv.w };
    float dwv[4]  = { 0.f, 0.f, 0.f, 0.f };
#pragma unroll
    for (int j = 0; j < TOPKK; ++j) {
        const int p = gidx[j];
#pragma unroll
        for (int dd = 0; dd < 4; ++dd) {
            const float4 da = *(const float4*)&ldown[(size_t)p * DIN * RR + (size_t)(d0 + dd) * RR];
            const float4 db = *(const float4*)&ldown[(size_t)p * DIN * RR + (size_t)(d0 + dd) * RR + 4];
            dwv[dd] += da.x * c[j][0] + da.y * c[j][1] + da.z * c[j][2] + da.w * c[j][3]
                     + db.x * c[j][4] + db.y * c[j][5] + db.z * c[j][6] + db.w * c[j][7];
        }
    }
    bf16x4 b0 = { (__bf16)outv[0], (__bf16)outv[1], (__bf16)outv[2], (__bf16)outv[3] };
    bf16x4 b1 = { (__bf16)(outv[0] + dwv[0]), (__bf16)(outv[1] + dwv[1]),
                  (__bf16)(outv[2] + dwv[2]), (__bf16)(outv[3] + dwv[3]) };
    *(bf16x4*)&Wb0[(size_t)o * DIN + d0] = b0;
    *(bf16x4*)&Wb1[(size_t)o * DIN + d0] = b1;
}

// ---------------- K4: 128x256 GEMM, f32-A converted in-kernel -----------------
// Same structure/layout/B-path as R7 (validated: 0 bank conflicts). A is now
// staged reg->cvt->ds_write from the f32 input: per slab, each thread loads
// 2x dwordx4 (8 f32), converts to bf16x8, one ds_write_b128 into the SAME
// swizzled A layout the reader uses (write-side XOR == read-side XOR).
// FIFO vmcnt: steady outstanding entering step s = [B(s)x2, Areg(s+1)x2,
// B(s+1)x2]; vmcnt(2) retires B(s)+Areg(s+1) exactly, B(s+1) stays in flight.
__global__ __launch_bounds__(512, 4) void k4_gemm(const float* __restrict__ A,
                                                  const __bf16* __restrict__ B0,
                                                  const __bf16* __restrict__ B1,
                                                  float* __restrict__ C) {
    __shared__ ushort lds[36864];              // 72 KB; slab p at p*12288 ushorts
    const int bid = blockIdx.x;                // 0..511
    const int xcd = bid & 7;
    const int idx = bid >> 3;                  // 0..63
    const int tm  = xcd * 16 + (idx >> 2);     // 0..127 ; same-XCD blocks share A-panels
    const int tn  = idx & 3;                   // 0..3
    const __bf16* __restrict__ Bt = (tm >= 64) ? B1 : B0;   // rows >= 8192 get +delta

    const int tix  = threadIdx.x;
    const int lane = tix & 63;
    const int wid  = tix >> 6;                 // 0..7
    const int wm = wid >> 2, wn = wid & 3;     // 2M x 4N wave grid

    // ---- A staging (reg->cvt->ds_write): thread tix -> row r=tix>>2, chunk c=tix&3
    const int ar = tix >> 2;                   // 0..127
    const int ac = tix & 3;                    // 8-float chunk
    const f32x4* __restrict__ pA = (const f32x4*)(A + ((size_t)(tm * 128 + ar)) * 1024 + ac * 8);
    const int awrp  = tix >> 3;                        // rowpair 0..63
    const int awslot= ((tix & 3) + 4 * ((tix >> 2) & 1)) ^ (awrp & 7);
    const int awoff = awrp * 64 + awslot * 8;          // ushorts within A region

    // ---- B staging lane geometry (gload_lds, pre-swizzled global source):
    const int rpl  = lane >> 3;                // local rowpair 0..7
    const int sl   = (lane & 7) ^ rpl;         // logical c + 4*parity
    const int srow = rpl * 2 + (sl >> 2);      // 0..15
    const int sc   = sl & 3;                   // 16B k-chunk
    const char* gB = (const char*)Bt + ((size_t)(tn*256 + wid*32 + srow)) * 2048 + sc * 16;
    const int ldsBst = 4096 + wid * 1024;      // ushort idx within slab (B region)

    // ---- reader lane geometry (validated R5-R7):
    const int rhalf = (lane & 15) >> 1;
    const int slot  = ((lane >> 4) + 4 * (lane & 1)) ^ rhalf;
    const int aoff  = (wm * 32 + rhalf) * 64 + slot * 8;          // + p*12288 + mi*512
    const int boff  = 4096 + (wn * 32 + rhalf) * 64 + slot * 8;   // + p*12288 + ni*512

    f32x4 acc[4][4];
#pragma unroll
    for (int i = 0; i < 4; ++i)
#pragma unroll
        for (int j = 0; j < 4; ++j) acc[i][j] = (f32x4){0.f, 0.f, 0.f, 0.f};

    auto issueB = [&](int s) {
        const int p = s % 3;
        const size_t kb = (size_t)s * 64;      // 32 bf16 = 64 B per k-slab
#pragma unroll
        for (int j = 0; j < 2; ++j) {
            __builtin_amdgcn_global_load_lds(
                (const __attribute__((address_space(1))) void*)(gB + (size_t)j * 32768 + kb),
                (__attribute__((address_space(3))) void*)&lds[p * 12288 + ldsBst + j * 512],
                16, 0, 0);
        }
    };

    auto writeA = [&](int s, f32x4 a0, f32x4 a1) {
        const int p = s % 3;
        bf16x8 v = { (__bf16)a0[0], (__bf16)a0[1], (__bf16)a0[2], (__bf16)a0[3],
                     (__bf16)a1[0], (__bf16)a1[1], (__bf16)a1[2], (__bf16)a1[3] };
        *(bf16x8*)&lds[p * 12288 + awoff] = v;
    };

    auto computeSlab = [&](int s) {
        const int p = s % 3;
        const ushort* aB = &lds[p * 12288 + aoff];
        const ushort* bB = &lds[p * 12288 + boff];
        bf16x8 a[4], b[4];
#pragma unroll
        for (int mi = 0; mi < 4; ++mi) a[mi] = *(const bf16x8*)(aB + mi * 512);
#pragma unroll
        for (int ni = 0; ni < 4; ++ni) b[ni] = *(const bf16x8*)(bB + ni * 512);
        __builtin_amdgcn_s_setprio(1);
#pragma unroll
        for (int mi = 0; mi < 4; ++mi)
#pragma unroll
            for (int ni = 0; ni < 4; ++ni)
                acc[mi][ni] = __builtin_amdgcn_mfma_f32_16x16x32_bf16(
                    a[mi], b[ni], acc[mi][ni], 0, 0, 0);
        __builtin_amdgcn_s_setprio(0);
    };

    // ---- prologue: A(0),B(0),A(1),B(1) in flight; land+write A(0).
    f32x4 pa0 = pA[0], pa1 = pA[1];            // A(0)
    issueB(0);
    f32x4 na0 = pA[8], na1 = pA[9];            // A(1)
    issueB(1);
    asm volatile("s_waitcnt vmcnt(6)" ::: "memory");   // retire A(0) regs
    writeA(0, pa0, pa1);

#pragma unroll 1
    for (int s = 0; s < 32; ++s) {
        if (s < 31) {
            asm volatile("s_waitcnt vmcnt(2)" ::: "memory");  // retire B(s)+Areg(s+1)
            writeA(s + 1, na0, na1);
        } else {
            asm volatile("s_waitcnt vmcnt(0)" ::: "memory");
        }
        if (s < 30) {
            na0 = pA[(size_t)(s + 2) * 8];
            na1 = pA[(size_t)(s + 2) * 8 + 1];
            issueB(s + 2);
        }
        asm volatile("s_waitcnt lgkmcnt(0)" ::: "memory");    // ds_writes visible
        __builtin_amdgcn_s_barrier();
        asm volatile("" ::: "memory");
        computeSlab(s);
        asm volatile("" ::: "memory");
        __builtin_amdgcn_s_barrier();
    }

    // epilogue: D col = lane&15, row = (lane>>4)*4 + r
#pragma unroll
    for (int mi = 0; mi < 4; ++mi) {
#pragma unroll
        for (int r = 0; r < 4; ++r) {
            const int grow = tm * 128 + wm * 64 + mi * 16 + (lane >> 4) * 4 + r;
            float* cp = C + (size_t)grow * 1024 + tn * 256 + wn * 64 + (lane & 15);
#pragma unroll
            for (int ni = 0; ni < 4; ++ni) cp[ni * 16] = acc[mi][ni][r];
        }
    }
}

extern "C" void kernel_launch(void* const* d_in, const int* in_sizes, int n_in,
                              void* d_out, int out_size, void* d_ws, size_t ws_size,
                              hipStream_t stream) {
    const float* in     = (const float*)d_in[0];
    const float* W      = (const float*)d_in[1];
    const float* ldown  = (const float*)d_in[2];
    const float* lup    = (const float*)d_in[3];
    const float* lroute = (const float*)d_in[4];
    const int*   taskid = (const int*)d_in[5];
    float* out = (float*)d_out;

    // workspace carve (~12.1 MB) — no inB anymore
    __bf16* Wb0     = (__bf16*)d_ws;                            // 2 MB
    __bf16* Wb1     = Wb0 + (size_t)DOUT * DIN;                 // 2 MB
    float*  partial2= (float*)(Wb1 + (size_t)DOUT * DIN);       // 32 KB
    float*  gate    = partial2 + 8 * DIN;
    int*    gidx    = (int*)(gate + TOPKK);
    float*  partial = (float*)(gidx + 64);                      // 8 MB

    kA_colsum<<<2048, 256, 0, stream>>>(in, partial);
    k1b_reduce<<<32, 256, 0, stream>>>(partial, partial2);
    k2_gate<<<1, 256, 0, stream>>>(partial2, lroute, taskid, gate, gidx);
    k3_weights<<<1024, 256, 0, stream>>>(W, ldown, lup, gate, gidx, Wb0, Wb1);
    k4_gemm<<<512, 512, 0, stream>>>(in, Wb0, Wb1, out);
}